// Round 17
// baseline (371.247 us; speedup 1.0000x reference)
//
#include <hip/hip_runtime.h>

#define NPATH  2048
#define DIM    64
#define NSTEPS 500
#define PPW    16   // paths per tile (one block per tile)
#define NR     8    // noise ring slots (LDS)

typedef __attribute__((ext_vector_type(8))) short bf16x8;
typedef __attribute__((ext_vector_type(4))) float f32x4;

union FragU { bf16x8 v; unsigned int u[4]; };

__device__ __forceinline__ unsigned int pk_bf16(float lo, float hi) {
    unsigned int r;
    asm("v_cvt_pk_bf16_f32 %0, %1, %2" : "=v"(r) : "v"(lo), "v"(hi));
    return r;
}

#define MFMA __builtin_amdgcn_mfma_f32_16x16x32_bf16

// Producer-consumer wave specialization around the sigma-closed recurrence.
// Block = 128 threads = 2 waves, one 16-path tile.
//   Wave 0 (consumer): r10-verified sigma recurrence entirely in registers
//     (MFMA C-output layout == next step's B-fragment layout, closed by 8
//     cvt_pk). Its only global ops are output stores (never waited on);
//     its only LDS reads are the noise slot + dtp -- both off the MFMA chain.
//   Wave 1 (producer): owns ALL dW traffic. Loads step q to regs (PA/PB
//     alternating), ds_writes slot (q)%8 one phase later, stays 4 phases
//     ahead of consumption. All HBM latency/waits live on this wave only.
// One raw s_barrier per phase; producer drains lgkmcnt before it. Slot
// write/read distance is 4 mod 8 in both directions => race-free.
__attribute__((amdgpu_waves_per_eu(1, 1)))
__global__ __launch_bounds__(128, 1) void sde_pc_kernel(
    const float* __restrict__ x0,
    const float* __restrict__ dW,
    const float* __restrict__ drift,
    const float* __restrict__ drift_bias,
    const float* __restrict__ diffusion,
    const float* __restrict__ diffusion_bias,
    const float* __restrict__ ts,
    float* __restrict__ out)
{
    __shared__ __align__(16) float nz[NR][PPW * DIM];   // 32 KB noise ring
    __shared__ float2 dtp[NSTEPS + 1];

    const int tid  = threadIdx.x;
    const int wv   = tid >> 6;          // 0 = consumer, 1 = producer
    const int lane = tid & 63;
    const int c    = lane & 15;         // path within tile / MFMA col
    const int h    = lane >> 4;         // k-slot group
    const int o8h  = 8 * h;
    const int p    = blockIdx.x * PPW + c;

    for (int i = tid; i < NSTEPS; i += 128) {
        const float d = ts[i + 1] - ts[i];          // f32-exact vs reference
        dtp[i] = make_float2(d, sqrtf(d));
    }
    if (tid == 0) dtp[NSTEPS] = make_float2(0.f, 0.f);

    static const int oo[4] = {0, 4, 32, 36};        // dim offset of block beta

    const float* pdw = dW + (size_t)p * NSTEPS * DIM + o8h;
    float* const nzl = &nz[0][0] + lane * 16;       // lane strip in slot 0
    const int SLOT = PPW * DIM;                     // floats per slot

    // ---- consumer-persistent state ----
    FragU mf[2][4][2];
    f32x4 bA[4], bC[4];
    f32x4 xs_[4];
    FragU xf0, xf1;
    float* pout = out;
    const f32x4 cz = {0.f, 0.f, 0.f, 0.f};
    // ---- producer-persistent state ----
    f32x4 PA[4], PB[4];

    if (wv == 0) {
        // sigma-permuted matrix fragments (r9/r10-verified), in VGPRs:
        // A_beta[row=c][k=32kk+8h+e] = M[sigma(beta,c)][32kk+8h+e]
#pragma unroll
        for (int mat = 0; mat < 2; ++mat) {
            const float* __restrict__ M = mat ? diffusion : drift;
#pragma unroll
            for (int b = 0; b < 4; ++b) {
                const int row = 32 * (b >> 1) + 8 * (c >> 2) + 4 * (b & 1) + (c & 3);
                const float* Mr = M + row * DIM + o8h;
#pragma unroll
                for (int kk = 0; kk < 2; ++kk) {
                    const f32x4 lo = *(const f32x4*)(Mr + 32 * kk);
                    const f32x4 hi = *(const f32x4*)(Mr + 32 * kk + 4);
                    mf[mat][b][kk].u[0] = pk_bf16(lo[0], lo[1]);
                    mf[mat][b][kk].u[1] = pk_bf16(lo[2], lo[3]);
                    mf[mat][b][kk].u[2] = pk_bf16(hi[0], hi[1]);
                    mf[mat][b][kk].u[3] = pk_bf16(hi[2], hi[3]);
                }
            }
        }
#pragma unroll
        for (int b = 0; b < 4; ++b) {
            bA[b] = *(const f32x4*)(drift_bias     + o8h + oo[b]);
            bC[b] = *(const f32x4*)(diffusion_bias + o8h + oo[b]);
        }
        pout = out + (size_t)p * (NSTEPS + 1) * DIM + o8h;
#pragma unroll
        for (int b = 0; b < 4; ++b) {
            xs_[b] = *(const f32x4*)(x0 + p * DIM + o8h + oo[b]);
            *(f32x4*)(pout + oo[b]) = xs_[b];           // ys[:,0,:]
        }
        pout += DIM;
        xf0.u[0] = pk_bf16(xs_[0][0], xs_[0][1]); xf0.u[1] = pk_bf16(xs_[0][2], xs_[0][3]);
        xf0.u[2] = pk_bf16(xs_[1][0], xs_[1][1]); xf0.u[3] = pk_bf16(xs_[1][2], xs_[1][3]);
        xf1.u[0] = pk_bf16(xs_[2][0], xs_[2][1]); xf1.u[1] = pk_bf16(xs_[2][2], xs_[2][3]);
        xf1.u[2] = pk_bf16(xs_[3][0], xs_[3][1]); xf1.u[3] = pk_bf16(xs_[3][2], xs_[3][3]);
    } else {
        // prologue: steps 0..3 -> slots 0..3; then issue steps 4,5 into PA,PB
#pragma unroll
        for (int s = 0; s < 4; ++s) {
            f32x4 t0 = *(const f32x4*)(pdw + (size_t)s * DIM + oo[0]);
            f32x4 t1 = *(const f32x4*)(pdw + (size_t)s * DIM + oo[1]);
            f32x4 t2 = *(const f32x4*)(pdw + (size_t)s * DIM + oo[2]);
            f32x4 t3 = *(const f32x4*)(pdw + (size_t)s * DIM + oo[3]);
            f32x4* wp = (f32x4*)(nzl + s * SLOT);
            wp[0] = t0; wp[1] = t1; wp[2] = t2; wp[3] = t3;
        }
#pragma unroll
        for (int b = 0; b < 4; ++b) {
            PA[b] = *(const f32x4*)(pdw + (size_t)4 * DIM + oo[b]);
            PB[b] = *(const f32x4*)(pdw + (size_t)5 * DIM + oo[b]);
        }
    }

    __syncthreads();      // one-time full drain: slots 0..3, mf, dtp ready

    float2 dts = dtp[0];
    const float2* pdt = &dtp[1];
    const float* pdwp = pdw + 6 * DIM;   // producer load cursor (step 6)

    // Phase K (within an 8-aligned group): consumer eats slot K; producer
    // writes slot (K+4)&7 from PREG (holding step pb+K+4), reloads PREG
    // with step pb+K+6. DOL/DOW gate the tail.
#define PHASE(K, PREG, DOL, DOW)                                              \
    {                                                                         \
        if (wv) {                                                             \
            if (DOW) {                                                        \
                f32x4* wp = (f32x4*)(nzl + ((K + 4) & 7) * SLOT);             \
                wp[0] = PREG[0]; wp[1] = PREG[1];                             \
                wp[2] = PREG[2]; wp[3] = PREG[3];                             \
            }                                                                 \
            if (DOL) {                                                        \
                PREG[0] = *(const f32x4*)(pdwp + (K) * DIM + oo[0]);          \
                PREG[1] = *(const f32x4*)(pdwp + (K) * DIM + oo[1]);          \
                PREG[2] = *(const f32x4*)(pdwp + (K) * DIM + oo[2]);          \
                PREG[3] = *(const f32x4*)(pdwp + (K) * DIM + oo[3]);          \
            }                                                                 \
            asm volatile("s_waitcnt lgkmcnt(0)" ::: "memory");                \
        } else {                                                              \
            const f32x4* Rp = (const f32x4*)(nzl + (K) * SLOT);               \
            const f32x4 Rr0 = Rp[0], Rr1 = Rp[1], Rr2 = Rp[2], Rr3 = Rp[3];   \
            const float2 dtn = *pdt++;                                        \
            _Pragma("unroll")                                                 \
            for (int b = 0; b < 4; ++b) {                                     \
                const f32x4 adA = MFMA(mf[0][b][0].v, xf0.v, bA[b], 0, 0, 0); \
                const f32x4 adB = MFMA(mf[0][b][1].v, xf1.v, cz,    0, 0, 0); \
                const f32x4 ciA = MFMA(mf[1][b][0].v, xf0.v, bC[b], 0, 0, 0); \
                const f32x4 ciB = MFMA(mf[1][b][1].v, xf1.v, cz,    0, 0, 0); \
                const f32x4 Rb = (b == 0) ? Rr0 : (b == 1) ? Rr1              \
                                : (b == 2) ? Rr2 : Rr3;                       \
                f32x4 xn;                                                     \
                _Pragma("unroll")                                             \
                for (int j = 0; j < 4; ++j)                                   \
                    xn[j] = fmaf(dts.x, adA[j] + adB[j], xs_[b][j])           \
                            + (ciA[j] + ciB[j]) * (dts.y * Rb[j]);            \
                xs_[b] = xn;                                                  \
                *(f32x4*)(pout + oo[b]) = xn;                                 \
            }                                                                 \
            xf0.u[0] = pk_bf16(xs_[0][0], xs_[0][1]);                         \
            xf0.u[1] = pk_bf16(xs_[0][2], xs_[0][3]);                         \
            xf0.u[2] = pk_bf16(xs_[1][0], xs_[1][1]);                         \
            xf0.u[3] = pk_bf16(xs_[1][2], xs_[1][3]);                         \
            xf1.u[0] = pk_bf16(xs_[2][0], xs_[2][1]);                         \
            xf1.u[1] = pk_bf16(xs_[2][2], xs_[2][3]);                         \
            xf1.u[2] = pk_bf16(xs_[3][0], xs_[3][1]);                         \
            xf1.u[3] = pk_bf16(xs_[3][2], xs_[3][3]);                         \
            pout += DIM;                                                      \
            dts = dtn;                                                        \
        }                                                                     \
        __builtin_amdgcn_s_barrier();                                         \
    }

    // main: it=0..60 -> phases 0..487 (all loads/writes in range)
    for (int it = 0; it < 61; ++it) {
        PHASE(0, PA, 1, 1)
        PHASE(1, PB, 1, 1)
        PHASE(2, PA, 1, 1)
        PHASE(3, PB, 1, 1)
        PHASE(4, PA, 1, 1)
        PHASE(5, PB, 1, 1)
        PHASE(6, PA, 1, 1)
        PHASE(7, PB, 1, 1)
        pdwp += 8 * DIM;
    }
    // it=61: phases 488..495 -> writes steps 492..499; loads steps 494..499
    PHASE(0, PA, 1, 1)
    PHASE(1, PB, 1, 1)
    PHASE(2, PA, 1, 1)
    PHASE(3, PB, 1, 1)
    PHASE(4, PA, 1, 1)
    PHASE(5, PB, 1, 1)
    PHASE(6, PA, 0, 1)
    PHASE(7, PB, 0, 1)
    // tail: phases 496..499 (slots 0..3, written at phases 492..495)
    PHASE(0, PA, 0, 0)
    PHASE(1, PB, 0, 0)
    PHASE(2, PA, 0, 0)
    PHASE(3, PB, 0, 0)
#undef PHASE
}

extern "C" void kernel_launch(void* const* d_in, const int* in_sizes, int n_in,
                              void* d_out, int out_size, void* d_ws, size_t ws_size,
                              hipStream_t stream) {
    const float* x0             = (const float*)d_in[0];
    const float* dW             = (const float*)d_in[1];
    const float* drift          = (const float*)d_in[2];
    const float* drift_bias     = (const float*)d_in[3];
    const float* diffusion      = (const float*)d_in[4];
    const float* diffusion_bias = (const float*)d_in[5];
    const float* ts             = (const float*)d_in[6];
    float* out = (float*)d_out;

    dim3 grid(NPATH / PPW);   // 128 blocks (one 16-path tile each)
    dim3 block(128);          // 2 waves: consumer + producer
    hipLaunchKernelGGL(sde_pc_kernel, grid, block, 0, stream,
                       x0, dW, drift, drift_bias, diffusion, diffusion_bias,
                       ts, out);
}

// Round 18
// 369.871 us; speedup vs baseline: 1.0037x; 1.0037x over previous
//
#include <hip/hip_runtime.h>

#define NPATH  2048
#define DIM    64
#define NSTEPS 500
#define PPW    16   // paths per tile (one block per tile)
#define NR     8    // noise ring slots (LDS)

typedef __attribute__((ext_vector_type(8))) short bf16x8;
typedef __attribute__((ext_vector_type(4))) float f32x4;

union FragU { bf16x8 v; unsigned int u[4]; };

__device__ __forceinline__ unsigned int pk_bf16(float lo, float hi) {
    unsigned int r;
    asm("v_cvt_pk_bf16_f32 %0, %1, %2" : "=v"(r) : "v"(lo), "v"(hi));
    return r;
}

#define MFMA __builtin_amdgcn_mfma_f32_16x16x32_bf16

// Producer-consumer wave specialization around the sigma-closed recurrence
// (r17), with the two measured defects fixed:
//  (1) noise ring relayout [slot][b][lane] -> lane-stride 16B, the
//      conflict-free ds_*_b128 pattern (r17's lane*64B strip = 9.2M conflicts);
//  (2) producer register ring depth 4 (PA..PD): load step q+8 at phase q,
//      ds_write at phase q+4 (slack ~4 phases > HBM latency), consumer
//      reads at phase q+8. Slot write/read separation 4 phases both ways.
// Wave 0 (consumer): r10-verified sigma recurrence fully in registers; its
// global stores are fire-and-forget; slot read hides under the MFMA block.
// Wave 1 (producer): owns all dW traffic and all vmem waits.
__attribute__((amdgpu_waves_per_eu(1, 1)))
__global__ __launch_bounds__(128, 1) void sde_pc2_kernel(
    const float* __restrict__ x0,
    const float* __restrict__ dW,
    const float* __restrict__ drift,
    const float* __restrict__ drift_bias,
    const float* __restrict__ diffusion,
    const float* __restrict__ diffusion_bias,
    const float* __restrict__ ts,
    float* __restrict__ out)
{
    __shared__ __align__(16) f32x4 nz[NR][4][64];   // 32 KB noise ring
    __shared__ float2 dtp[NSTEPS + 1];

    const int tid  = threadIdx.x;
    const int wv   = tid >> 6;          // 0 = consumer, 1 = producer
    const int lane = tid & 63;
    const int c    = lane & 15;         // path within tile / MFMA col
    const int h    = lane >> 4;         // k-slot group
    const int o8h  = 8 * h;
    const int p    = blockIdx.x * PPW + c;

    for (int i = tid; i < NSTEPS; i += 128) {
        const float d = ts[i + 1] - ts[i];          // f32-exact vs reference
        dtp[i] = make_float2(d, sqrtf(d));
    }
    if (tid == 0) dtp[NSTEPS] = make_float2(0.f, 0.f);

    static const int oo[4] = {0, 4, 32, 36};        // dim offset of block beta

    const float* pdw = dW + (size_t)p * NSTEPS * DIM + o8h;

    // ---- consumer-persistent state ----
    FragU mf[2][4][2];
    f32x4 bA[4], bC[4];
    f32x4 xs_[4];
    FragU xf0, xf1;
    float* pout = out;
    const f32x4 cz = {0.f, 0.f, 0.f, 0.f};
    // ---- producer-persistent state (depth-4 register ring) ----
    f32x4 PA[4], PB[4], PC[4], PD[4];

    if (wv == 0) {
        // sigma-permuted matrix fragments (r9/r10-verified), in VGPRs:
        // A_beta[row=c][k=32kk+8h+e] = M[sigma(beta,c)][32kk+8h+e]
#pragma unroll
        for (int mat = 0; mat < 2; ++mat) {
            const float* __restrict__ M = mat ? diffusion : drift;
#pragma unroll
            for (int b = 0; b < 4; ++b) {
                const int row = 32 * (b >> 1) + 8 * (c >> 2) + 4 * (b & 1) + (c & 3);
                const float* Mr = M + row * DIM + o8h;
#pragma unroll
                for (int kk = 0; kk < 2; ++kk) {
                    const f32x4 lo = *(const f32x4*)(Mr + 32 * kk);
                    const f32x4 hi = *(const f32x4*)(Mr + 32 * kk + 4);
                    mf[mat][b][kk].u[0] = pk_bf16(lo[0], lo[1]);
                    mf[mat][b][kk].u[1] = pk_bf16(lo[2], lo[3]);
                    mf[mat][b][kk].u[2] = pk_bf16(hi[0], hi[1]);
                    mf[mat][b][kk].u[3] = pk_bf16(hi[2], hi[3]);
                }
            }
        }
#pragma unroll
        for (int b = 0; b < 4; ++b) {
            bA[b] = *(const f32x4*)(drift_bias     + o8h + oo[b]);
            bC[b] = *(const f32x4*)(diffusion_bias + o8h + oo[b]);
        }
        pout = out + (size_t)p * (NSTEPS + 1) * DIM + o8h;
#pragma unroll
        for (int b = 0; b < 4; ++b) {
            xs_[b] = *(const f32x4*)(x0 + p * DIM + o8h + oo[b]);
            *(f32x4*)(pout + oo[b]) = xs_[b];           // ys[:,0,:]
        }
        pout += DIM;
        xf0.u[0] = pk_bf16(xs_[0][0], xs_[0][1]); xf0.u[1] = pk_bf16(xs_[0][2], xs_[0][3]);
        xf0.u[2] = pk_bf16(xs_[1][0], xs_[1][1]); xf0.u[3] = pk_bf16(xs_[1][2], xs_[1][3]);
        xf1.u[0] = pk_bf16(xs_[2][0], xs_[2][1]); xf1.u[1] = pk_bf16(xs_[2][2], xs_[2][3]);
        xf1.u[2] = pk_bf16(xs_[3][0], xs_[3][1]); xf1.u[3] = pk_bf16(xs_[3][2], xs_[3][3]);
    } else {
        // prologue: steps 0..3 -> slots 0..3; PREGs <- steps 4..7
#pragma unroll
        for (int s = 0; s < 4; ++s)
#pragma unroll
            for (int b = 0; b < 4; ++b)
                nz[s][b][lane] = *(const f32x4*)(pdw + (size_t)s * DIM + oo[b]);
#pragma unroll
        for (int b = 0; b < 4; ++b) {
            PA[b] = *(const f32x4*)(pdw + (size_t)4 * DIM + oo[b]);
            PB[b] = *(const f32x4*)(pdw + (size_t)5 * DIM + oo[b]);
            PC[b] = *(const f32x4*)(pdw + (size_t)6 * DIM + oo[b]);
            PD[b] = *(const f32x4*)(pdw + (size_t)7 * DIM + oo[b]);
        }
    }

    __syncthreads();      // one-time full drain: slots 0..3, mf, dtp ready

    float2 dts = dtp[0];
    const float2* pdt = &dtp[1];
    const float* pdwp = pdw + 8 * DIM;   // producer load cursor (step 8)

    // Phase q (K = q mod 8): consumer eats slot K (step q); producer writes
    // step q+4 (PREG, loaded at phase q-4) to slot (K+4)&7, then reloads
    // PREG with step q+8. DOL/DOW gate the tail.
#define PHASE(K, PREG, DOL, DOW)                                              \
    {                                                                         \
        if (wv) {                                                             \
            if (DOW) {                                                        \
                nz[(K + 4) & 7][0][lane] = PREG[0];                           \
                nz[(K + 4) & 7][1][lane] = PREG[1];                           \
                nz[(K + 4) & 7][2][lane] = PREG[2];                           \
                nz[(K + 4) & 7][3][lane] = PREG[3];                           \
            }                                                                 \
            if (DOL) {                                                        \
                PREG[0] = *(const f32x4*)(pdwp + (K) * DIM + oo[0]);          \
                PREG[1] = *(const f32x4*)(pdwp + (K) * DIM + oo[1]);          \
                PREG[2] = *(const f32x4*)(pdwp + (K) * DIM + oo[2]);          \
                PREG[3] = *(const f32x4*)(pdwp + (K) * DIM + oo[3]);          \
            }                                                                 \
            asm volatile("s_waitcnt lgkmcnt(0)" ::: "memory");                \
        } else {                                                              \
            const f32x4 Rr0 = nz[K][0][lane];                                 \
            const f32x4 Rr1 = nz[K][1][lane];                                 \
            const f32x4 Rr2 = nz[K][2][lane];                                 \
            const f32x4 Rr3 = nz[K][3][lane];                                 \
            const float2 dtn = *pdt++;                                        \
            _Pragma("unroll")                                                 \
            for (int b = 0; b < 4; ++b) {                                     \
                const f32x4 adA = MFMA(mf[0][b][0].v, xf0.v, bA[b], 0, 0, 0); \
                const f32x4 adB = MFMA(mf[0][b][1].v, xf1.v, cz,    0, 0, 0); \
                const f32x4 ciA = MFMA(mf[1][b][0].v, xf0.v, bC[b], 0, 0, 0); \
                const f32x4 ciB = MFMA(mf[1][b][1].v, xf1.v, cz,    0, 0, 0); \
                const f32x4 Rb = (b == 0) ? Rr0 : (b == 1) ? Rr1              \
                                : (b == 2) ? Rr2 : Rr3;                       \
                f32x4 xn;                                                     \
                _Pragma("unroll")                                             \
                for (int j = 0; j < 4; ++j)                                   \
                    xn[j] = fmaf(dts.x, adA[j] + adB[j], xs_[b][j])           \
                            + (ciA[j] + ciB[j]) * (dts.y * Rb[j]);            \
                xs_[b] = xn;                                                  \
                *(f32x4*)(pout + oo[b]) = xn;                                 \
            }                                                                 \
            xf0.u[0] = pk_bf16(xs_[0][0], xs_[0][1]);                         \
            xf0.u[1] = pk_bf16(xs_[0][2], xs_[0][3]);                         \
            xf0.u[2] = pk_bf16(xs_[1][0], xs_[1][1]);                         \
            xf0.u[3] = pk_bf16(xs_[1][2], xs_[1][3]);                         \
            xf1.u[0] = pk_bf16(xs_[2][0], xs_[2][1]);                         \
            xf1.u[1] = pk_bf16(xs_[2][2], xs_[2][3]);                         \
            xf1.u[2] = pk_bf16(xs_[3][0], xs_[3][1]);                         \
            xf1.u[3] = pk_bf16(xs_[3][2], xs_[3][3]);                         \
            pout += DIM;                                                      \
            dts = dtn;                                                        \
        }                                                                     \
        __builtin_amdgcn_s_barrier();                                         \
    }

    // main: 61 groups of 8 -> phases 0..487 (loads steps 8..495... all valid)
    for (int it = 0; it < 61; ++it) {
        PHASE(0, PA, 1, 1)
        PHASE(1, PB, 1, 1)
        PHASE(2, PC, 1, 1)
        PHASE(3, PD, 1, 1)
        PHASE(4, PA, 1, 1)
        PHASE(5, PB, 1, 1)
        PHASE(6, PC, 1, 1)
        PHASE(7, PD, 1, 1)
        pdwp += 8 * DIM;
    }
    // phases 488..491: load steps 496..499, write steps 492..495
    PHASE(0, PA, 1, 1)
    PHASE(1, PB, 1, 1)
    PHASE(2, PC, 1, 1)
    PHASE(3, PD, 1, 1)
    // phases 492..495: write steps 496..499 (PREGs loaded at 488..491)
    PHASE(4, PA, 0, 1)
    PHASE(5, PB, 0, 1)
    PHASE(6, PC, 0, 1)
    PHASE(7, PD, 0, 1)
    // phases 496..499: consume slots 0..3 (steps 496..499)
    PHASE(0, PA, 0, 0)
    PHASE(1, PB, 0, 0)
    PHASE(2, PC, 0, 0)
    PHASE(3, PD, 0, 0)
#undef PHASE
}

extern "C" void kernel_launch(void* const* d_in, const int* in_sizes, int n_in,
                              void* d_out, int out_size, void* d_ws, size_t ws_size,
                              hipStream_t stream) {
    const float* x0             = (const float*)d_in[0];
    const float* dW             = (const float*)d_in[1];
    const float* drift          = (const float*)d_in[2];
    const float* drift_bias     = (const float*)d_in[3];
    const float* diffusion      = (const float*)d_in[4];
    const float* diffusion_bias = (const float*)d_in[5];
    const float* ts             = (const float*)d_in[6];
    float* out = (float*)d_out;

    dim3 grid(NPATH / PPW);   // 128 blocks (one 16-path tile each)
    dim3 block(128);          // 2 waves: consumer + producer
    hipLaunchKernelGGL(sde_pc2_kernel, grid, block, 0, stream,
                       x0, dW, drift, drift_bias, diffusion, diffusion_bias,
                       ts, out);
}